// Round 5
// baseline (1478.307 us; speedup 1.0000x reference)
//
#include <hip/hip_runtime.h>
#include <hip/hip_cooperative_groups.h>

namespace cg = cooperative_groups;

#define NN 50000
#define TT 10
#define EE 1000000
#define BLOCK 512
#define GRID_BLOCKS 256
#define GROUPS 8
#define BPG 32              // blocks per group
#define NPG 6250            // nodes per group (8*6250 = 50000)

__device__ __forceinline__ float sigmoidf_(float v) { return 1.0f / (1.0f + __expf(-v)); }
__device__ __forceinline__ float reluf_(float v) { return v > 0.0f ? v : 0.0f; }

// MLP1: feat[9] -> relu(9x32) -> relu(32x32) -> sigmoid(32x1)
__device__ __forceinline__ float mlp1_eval(const float* feat,
                                           const float* s_w1, const float* s_b1,
                                           const float* s_w2, const float* s_b2,
                                           const float* s_w3, float s_b3) {
    float h1[32];
#pragma unroll
    for (int j = 0; j < 32; ++j) {
        float acc = s_b1[j];
#pragma unroll
        for (int i = 0; i < 9; ++i) acc += feat[i] * s_w1[i * 32 + j];
        h1[j] = reluf_(acc);
    }
    float acc3 = s_b3;
#pragma unroll
    for (int j2 = 0; j2 < 32; ++j2) {
        float acc = s_b2[j2];
#pragma unroll
        for (int i = 0; i < 32; ++i) acc += h1[i] * s_w2[i * 32 + j2];
        acc3 += reluf_(acc) * s_w3[j2];
    }
    return sigmoidf_(acc3);
}

__global__ void __launch_bounds__(BLOCK, 1)
fused_kernel(const float* __restrict__ x, const int* __restrict__ ei,
             const float* __restrict__ ea,
             const float* __restrict__ m1w1, const float* __restrict__ m1b1,
             const float* __restrict__ m1w2, const float* __restrict__ m1b2,
             const float* __restrict__ m1w3, const float* __restrict__ m1b3,
             const float* __restrict__ m2w1, const float* __restrict__ m2b1,
             const float* __restrict__ m2w2, const float* __restrict__ m2b2,
             const float* __restrict__ ow1, const float* __restrict__ ob1,
             const float* __restrict__ ow2, const float* __restrict__ ob2,
             float* __restrict__ out,
             float* __restrict__ msg_base, float* __restrict__ partials,
             float* __restrict__ eaT, int fast_ea) {
    __shared__ float s_w1[288], s_b1[32], s_w2[1024], s_b2[32], s_w3[32];
    __shared__ float s_m2w1[320], s_m2b1[32], s_m2w2[256], s_m2b2[8];
    __shared__ float s_ow1[128], s_ob1[16], s_ow2[16];
    __shared__ float s_b3s, s_ob2s;
    __shared__ float s_tab[NPG];          // 25 KB dst-accumulation table

    const int tid = threadIdx.x;
    for (int i = tid; i < 288; i += BLOCK) s_w1[i] = m1w1[i];
    for (int i = tid; i < 1024; i += BLOCK) s_w2[i] = m1w2[i];
    for (int i = tid; i < 320; i += BLOCK) s_m2w1[i] = m2w1[i];
    for (int i = tid; i < 256; i += BLOCK) s_m2w2[i] = m2w2[i];
    for (int i = tid; i < 128; i += BLOCK) s_ow1[i] = ow1[i];
    if (tid < 32) {
        s_b1[tid] = m1b1[tid];
        s_b2[tid] = m1b2[tid];
        s_w3[tid] = m1w3[tid];
        s_m2b1[tid] = m2b1[tid];
    }
    if (tid < 16) { s_ob1[tid] = ob1[tid]; s_ow2[tid] = ow2[tid]; }
    if (tid < 8) s_m2b2[tid] = m2b2[tid];
    if (tid == 0) { s_b3s = m1b3[0]; s_ob2s = ob2[0]; }
    __syncthreads();

    cg::grid_group grid = cg::this_grid();
    const int gid = blockIdx.x * BLOCK + tid;
    const int gsize = GRID_BLOCKS * BLOCK;
    const int g = blockIdx.x & (GROUPS - 1);    // my dst group
    const int b = blockIdx.x >> 3;              // block index within group (0..31)
    const int lo = g * NPG;

    // ---- Phase A: ea transpose + msg_base init (hidden = 0) ----
    if (fast_ea) {
        for (int e = gid; e < EE; e += gsize) {
            const float2* p = reinterpret_cast<const float2*>(ea + (size_t)e * TT);
            float2 a0 = p[0], a1 = p[1], a2 = p[2], a3 = p[3], a4 = p[4];
            eaT[0 * EE + e] = a0.x; eaT[1 * EE + e] = a0.y;
            eaT[2 * EE + e] = a1.x; eaT[3 * EE + e] = a1.y;
            eaT[4 * EE + e] = a2.x; eaT[5 * EE + e] = a2.y;
            eaT[6 * EE + e] = a3.x; eaT[7 * EE + e] = a3.y;
            eaT[8 * EE + e] = a4.x; eaT[9 * EE + e] = a4.y;
        }
    }

    float hid[8];
#pragma unroll
    for (int k = 0; k < 8; ++k) hid[k] = 0.0f;

    if (gid < NN) {
        float feat[9];
        feat[0] = x[(size_t)gid * 20];       // x[n][0][0]
#pragma unroll
        for (int k = 0; k < 8; ++k) feat[1 + k] = 0.0f;
        msg_base[gid] = mlp1_eval(feat, s_w1, s_b1, s_w2, s_b2, s_w3, s_b3s);
    }
    grid.sync();

    // ---- Frame loop ----
    for (int t = 0; t < TT; ++t) {
        // zero LDS table
        for (int i = tid; i < NPG; i += BLOCK) s_tab[i] = 0.0f;
        __syncthreads();

        // Scan phase: my group's 32 blocks partition all E edges;
        // keep edges whose dst falls in my group's node range -> LDS atomic.
        const int* srcp = ei + (size_t)t * EE;
        const int* dstp = ei + (size_t)TT * EE + (size_t)t * EE;
        const float* eat = fast_ea ? (eaT + (size_t)t * EE) : nullptr;
        for (int e = (b * BLOCK + tid) * 4; e < EE; e += BPG * BLOCK * 4) {
            int4 d4 = *reinterpret_cast<const int4*>(dstp + e);
            unsigned u0 = (unsigned)(d4.x - lo);
            unsigned u1 = (unsigned)(d4.y - lo);
            unsigned u2 = (unsigned)(d4.z - lo);
            unsigned u3 = (unsigned)(d4.w - lo);
            bool p0 = u0 < NPG, p1 = u1 < NPG, p2 = u2 < NPG, p3 = u3 < NPG;
            if (p0 | p1 | p2 | p3) {
                int4 s4 = *reinterpret_cast<const int4*>(srcp + e);
                float a0, a1, a2, a3;
                if (fast_ea) {
                    float4 a4 = *reinterpret_cast<const float4*>(eat + e);
                    a0 = a4.x; a1 = a4.y; a2 = a4.z; a3 = a4.w;
                } else {
                    a0 = ea[(size_t)(e + 0) * TT + t];
                    a1 = ea[(size_t)(e + 1) * TT + t];
                    a2 = ea[(size_t)(e + 2) * TT + t];
                    a3 = ea[(size_t)(e + 3) * TT + t];
                }
                if (p0) atomicAdd(&s_tab[u0], msg_base[s4.x] * a0);
                if (p1) atomicAdd(&s_tab[u1], msg_base[s4.y] * a1);
                if (p2) atomicAdd(&s_tab[u2], msg_base[s4.z] * a2);
                if (p3) atomicAdd(&s_tab[u3], msg_base[s4.w] * a3);
            }
        }
        __syncthreads();

        // publish partials: P[(g*BPG + b)*NPG + i]
        {
            float* myP = partials + (size_t)(g * BPG + b) * NPG;
            for (int i = tid; i < NPG; i += BLOCK) myP[i] = s_tab[i];
        }
        grid.sync();

        // Node phase
        if (gid < NN) {
            int g2 = gid / NPG;
            int i2 = gid - g2 * NPG;
            float a = 0.0f;
#pragma unroll
            for (int b2 = 0; b2 < BPG; ++b2)
                a += partials[(size_t)(g2 * BPG + b2) * NPG + i2];

            float x1v = x[(size_t)gid * 20 + 2 * t + 1];

            float uin[10];
            uin[0] = x1v;
#pragma unroll
            for (int k = 0; k < 8; ++k) uin[1 + k] = hid[k];
            uin[9] = a;

            float u1[32];
#pragma unroll
            for (int j = 0; j < 32; ++j) {
                float acc = s_m2b1[j];
#pragma unroll
                for (int i = 0; i < 10; ++i) acc += uin[i] * s_m2w1[i * 32 + j];
                u1[j] = reluf_(acc);
            }
#pragma unroll
            for (int k = 0; k < 8; ++k) {
                float acc = s_m2b2[k];
#pragma unroll
                for (int j = 0; j < 32; ++j) acc += u1[j] * s_m2w2[j * 8 + k];
                hid[k] = tanhf(reluf_(acc));
            }

            float o1[16];
#pragma unroll
            for (int l = 0; l < 16; ++l) {
                float acc = s_ob1[l];
#pragma unroll
                for (int k = 0; k < 8; ++k) acc += hid[k] * s_ow1[k * 16 + l];
                o1[l] = reluf_(acc);
            }
            float oo = s_ob2s;
#pragma unroll
            for (int l = 0; l < 16; ++l) oo += o1[l] * s_ow2[l];
            out[t * NN + gid] = sigmoidf_(oo);

            if (t < TT - 1) {
                float feat[9];
                feat[0] = x[(size_t)gid * 20 + 2 * (t + 1)];
#pragma unroll
                for (int k = 0; k < 8; ++k) feat[1 + k] = hid[k];
                msg_base[gid] = mlp1_eval(feat, s_w1, s_b1, s_w2, s_b2, s_w3, s_b3s);
            }
        }
        grid.sync();
    }
}

extern "C" void kernel_launch(void* const* d_in, const int* in_sizes, int n_in,
                              void* d_out, int out_size, void* d_ws, size_t ws_size,
                              hipStream_t stream) {
    (void)in_sizes; (void)n_in; (void)out_size;
    const float* x    = (const float*)d_in[0];
    const int*   ei   = (const int*)d_in[1];
    const float* ea   = (const float*)d_in[2];
    const float* m1w1 = (const float*)d_in[3];
    const float* m1b1 = (const float*)d_in[4];
    const float* m1w2 = (const float*)d_in[5];
    const float* m1b2 = (const float*)d_in[6];
    const float* m1w3 = (const float*)d_in[7];
    const float* m1b3 = (const float*)d_in[8];
    const float* m2w1 = (const float*)d_in[9];
    const float* m2b1 = (const float*)d_in[10];
    const float* m2w2 = (const float*)d_in[11];
    const float* m2b2 = (const float*)d_in[12];
    const float* ow1  = (const float*)d_in[13];
    const float* ob1  = (const float*)d_in[14];
    const float* ow2  = (const float*)d_in[15];
    const float* ob2  = (const float*)d_in[16];
    float* out = (float*)d_out;

    // workspace layout (floats):
    // [0, NN)                       msg_base
    // [NN, NN + GROUPS*BPG*NPG)     partials (8*32*6250 = 1.6M floats, 6.4 MB)
    // [.., + T*EE)                  eaT
    float* msg_base = (float*)d_ws;
    float* partials = msg_base + NN;
    float* eaT = partials + (size_t)GROUPS * BPG * NPG;

    size_t need_base = ((size_t)NN + (size_t)GROUPS * BPG * NPG) * sizeof(float);
    size_t need_ea = need_base + (size_t)TT * EE * sizeof(float);
    int fast_ea = (ws_size >= need_ea) ? 1 : 0;

    void* args[] = {
        (void*)&x, (void*)&ei, (void*)&ea,
        (void*)&m1w1, (void*)&m1b1, (void*)&m1w2, (void*)&m1b2,
        (void*)&m1w3, (void*)&m1b3,
        (void*)&m2w1, (void*)&m2b1, (void*)&m2w2, (void*)&m2b2,
        (void*)&ow1, (void*)&ob1, (void*)&ow2, (void*)&ob2,
        (void*)&out, (void*)&msg_base, (void*)&partials,
        (void*)&eaT, (void*)&fast_ea
    };
    hipLaunchCooperativeKernel((const void*)fused_kernel,
                               dim3(GRID_BLOCKS), dim3(BLOCK),
                               args, 0, stream);
}

// Round 6
// 1472.877 us; speedup vs baseline: 1.0037x; 1.0037x over previous
//
#include <hip/hip_runtime.h>
#include <hip/hip_cooperative_groups.h>

namespace cg = cooperative_groups;

#define NN 50000
#define TT 10
#define EE 1000000
#define BLOCK 1024
#define GRID_BLOCKS 256
#define GROUPS 8
#define BPG 32              // blocks per group (one group per XCD if round-robin)
#define NPG 6250            // nodes per group

__device__ __forceinline__ float sigmoidf_(float v) { return 1.0f / (1.0f + __expf(-v)); }
__device__ __forceinline__ float reluf_(float v) { return v > 0.0f ? v : 0.0f; }

// MLP1: feat[9] -> relu(9x32) -> relu(32x32) -> sigmoid(32x1)
__device__ __forceinline__ float mlp1_eval(const float* feat,
                                           const float* s_w1, const float* s_b1,
                                           const float* s_w2, const float* s_b2,
                                           const float* s_w3, float s_b3) {
    float h1[32];
#pragma unroll
    for (int j = 0; j < 32; ++j) {
        float acc = s_b1[j];
#pragma unroll
        for (int i = 0; i < 9; ++i) acc += feat[i] * s_w1[i * 32 + j];
        h1[j] = reluf_(acc);
    }
    float acc3 = s_b3;
#pragma unroll
    for (int j2 = 0; j2 < 32; ++j2) {
        float acc = s_b2[j2];
#pragma unroll
        for (int i = 0; i < 32; ++i) acc += h1[i] * s_w2[i * 32 + j2];
        acc3 += reluf_(acc) * s_w3[j2];
    }
    return sigmoidf_(acc3);
}

// 32-block group barrier (agent-scope acquire/release; correct on any XCD placement)
__device__ __forceinline__ void group_barrier(int* cnt, int* gen, int target) {
    __syncthreads();   // all waves of this block have drained their stores (vmcnt 0)
    if (threadIdx.x == 0) {
        int old = __hip_atomic_fetch_add(cnt, 1, __ATOMIC_ACQ_REL, __HIP_MEMORY_SCOPE_AGENT);
        if (old == BPG - 1) {
            __hip_atomic_store(cnt, 0, __ATOMIC_RELAXED, __HIP_MEMORY_SCOPE_AGENT);
            __hip_atomic_store(gen, target, __ATOMIC_RELEASE, __HIP_MEMORY_SCOPE_AGENT);
        } else {
            while (__hip_atomic_load(gen, __ATOMIC_ACQUIRE, __HIP_MEMORY_SCOPE_AGENT) < target) {}
        }
    }
    __syncthreads();
}

__global__ void __launch_bounds__(BLOCK, 4)
fused_kernel(const float* __restrict__ x, const int* __restrict__ ei,
             const float* __restrict__ ea,
             const float* __restrict__ m1w1, const float* __restrict__ m1b1,
             const float* __restrict__ m1w2, const float* __restrict__ m1b2,
             const float* __restrict__ m1w3, const float* __restrict__ m1b3,
             const float* __restrict__ m2w1, const float* __restrict__ m2b1,
             const float* __restrict__ m2w2, const float* __restrict__ m2b2,
             const float* __restrict__ ow1, const float* __restrict__ ob1,
             const float* __restrict__ ow2, const float* __restrict__ ob2,
             float* __restrict__ out,
             float* __restrict__ msg_base, float* __restrict__ partials,
             int* __restrict__ ibar, float* __restrict__ eaT,
             float* __restrict__ xa, float* __restrict__ xb,
             int fast_ea, int fast_x) {
    __shared__ float s_w1[288], s_b1[32], s_w2[1024], s_b2[32], s_w3[32];
    __shared__ float s_m2w1[320], s_m2b1[32], s_m2w2[256], s_m2b2[8];
    __shared__ float s_ow1[128], s_ob1[16], s_ow2[16];
    __shared__ float s_b3s, s_ob2s;
    __shared__ float s_tab[NPG];          // 25 KB dst-accumulation table

    const int tid = threadIdx.x;
    for (int i = tid; i < 288; i += BLOCK) s_w1[i] = m1w1[i];
    for (int i = tid; i < 1024; i += BLOCK) s_w2[i] = m1w2[i];
    for (int i = tid; i < 320; i += BLOCK) s_m2w1[i] = m2w1[i];
    for (int i = tid; i < 256; i += BLOCK) s_m2w2[i] = m2w2[i];
    for (int i = tid; i < 128; i += BLOCK) s_ow1[i] = ow1[i];
    if (tid < 32) {
        s_b1[tid] = m1b1[tid];
        s_b2[tid] = m1b2[tid];
        s_w3[tid] = m1w3[tid];
        s_m2b1[tid] = m2b1[tid];
    }
    if (tid < 16) { s_ob1[tid] = ob1[tid]; s_ow2[tid] = ow2[tid]; }
    if (tid < 8) s_m2b2[tid] = m2b2[tid];
    if (tid == 0) { s_b3s = m1b3[0]; s_ob2s = ob2[0]; }
    __syncthreads();

    cg::grid_group grid = cg::this_grid();
    const int g = blockIdx.x & (GROUPS - 1);     // group == XCD under round-robin
    const int b = blockIdx.x >> 3;               // block within group, 0..31
    const int gid = blockIdx.x * BLOCK + tid;
    const int glid = b * BLOCK + tid;            // 0..32767 within group
    const int lo = g * NPG;
    int* cnt = ibar + g;
    int* gen = ibar + GROUPS + g;

    // ---- Init phase ----
    if (gid < 2 * GROUPS) ibar[gid] = 0;
    if (fast_ea) {
        for (int e = gid; e < EE; e += GRID_BLOCKS * BLOCK) {
            const float2* p = reinterpret_cast<const float2*>(ea + (size_t)e * TT);
            float2 a0 = p[0], a1 = p[1], a2 = p[2], a3 = p[3], a4 = p[4];
            eaT[0 * EE + e] = a0.x; eaT[1 * EE + e] = a0.y;
            eaT[2 * EE + e] = a1.x; eaT[3 * EE + e] = a1.y;
            eaT[4 * EE + e] = a2.x; eaT[5 * EE + e] = a2.y;
            eaT[6 * EE + e] = a3.x; eaT[7 * EE + e] = a3.y;
            eaT[8 * EE + e] = a4.x; eaT[9 * EE + e] = a4.y;
        }
    }
    if (fast_x && gid < NN) {
        const float4* xp = reinterpret_cast<const float4*>(x + (size_t)gid * 20);
        float4 v0 = xp[0], v1 = xp[1], v2 = xp[2], v3 = xp[3], v4 = xp[4];
        float vv[20] = {v0.x, v0.y, v0.z, v0.w, v1.x, v1.y, v1.z, v1.w,
                        v2.x, v2.y, v2.z, v2.w, v3.x, v3.y, v3.z, v3.w,
                        v4.x, v4.y, v4.z, v4.w};
#pragma unroll
        for (int t = 0; t < TT; ++t) {
            xa[t * NN + gid] = vv[2 * t];
            xb[t * NN + gid] = vv[2 * t + 1];
        }
    }

    float hid[8];
#pragma unroll
    for (int k = 0; k < 8; ++k) hid[k] = 0.0f;

    if (gid < NN) {
        float feat[9];
        feat[0] = x[(size_t)gid * 20];
#pragma unroll
        for (int k = 0; k < 8; ++k) feat[1 + k] = 0.0f;
        msg_base[gid] = mlp1_eval(feat, s_w1, s_b1, s_w2, s_b2, s_w3, s_b3s);
    }
    grid.sync();   // init done: msg_base(0), eaT, xa/xb, ibar visible

    // ---- Frame loop: 1 grid.sync + 1 group barrier per frame ----
    for (int t = 0; t < TT; ++t) {
        const int* srcp = ei + (size_t)t * EE;
        const int* dstp = ei + (size_t)TT * EE + (size_t)t * EE;
        const float* eat = eaT + (size_t)t * EE;
        const int e0 = glid * 4;

        // Preload iteration-0 dst BEFORE the barrier (read-only input -> safe);
        // the load is in flight while we spin.
        int4 d4_0 = *reinterpret_cast<const int4*>(dstp + e0);

        if (t > 0) grid.sync();          // wait for msg_base(t) from node phase t-1
        for (int i = tid; i < NPG; i += BLOCK) s_tab[i] = 0.0f;
        __syncthreads();

        // Scan: my group's 32 blocks partition all E edges; filter dst in my range.
        for (int e = e0, it = 0; e < EE; e += BPG * BLOCK * 4, ++it) {
            int4 d4 = (it == 0) ? d4_0 : *reinterpret_cast<const int4*>(dstp + e);
            unsigned u0 = (unsigned)(d4.x - lo);
            unsigned u1 = (unsigned)(d4.y - lo);
            unsigned u2 = (unsigned)(d4.z - lo);
            unsigned u3 = (unsigned)(d4.w - lo);
            bool p0 = u0 < NPG, p1 = u1 < NPG, p2 = u2 < NPG, p3 = u3 < NPG;
            if (p0 | p1 | p2 | p3) {
                int4 s4 = *reinterpret_cast<const int4*>(srcp + e);
                float a0, a1, a2, a3;
                if (fast_ea) {
                    float4 a4 = *reinterpret_cast<const float4*>(eat + e);
                    a0 = a4.x; a1 = a4.y; a2 = a4.z; a3 = a4.w;
                } else {
                    a0 = ea[(size_t)(e + 0) * TT + t];
                    a1 = ea[(size_t)(e + 1) * TT + t];
                    a2 = ea[(size_t)(e + 2) * TT + t];
                    a3 = ea[(size_t)(e + 3) * TT + t];
                }
                if (p0) atomicAdd(&s_tab[u0], msg_base[s4.x] * a0);
                if (p1) atomicAdd(&s_tab[u1], msg_base[s4.y] * a1);
                if (p2) atomicAdd(&s_tab[u2], msg_base[s4.z] * a2);
                if (p3) atomicAdd(&s_tab[u3], msg_base[s4.w] * a3);
            }
        }
        __syncthreads();

        // Publish my block's partial table: [group][block][node] (contiguous)
        {
            float* myP = partials + ((size_t)g * BPG + b) * NPG;
            for (int i = tid; i < NPG; i += BLOCK) myP[i] = s_tab[i];
        }
        group_barrier(cnt, gen, t + 1);   // group-internal: edge -> node handoff

        // Node phase: group's first 6250 threads own its nodes (hidden in regs)
        if (glid < NPG) {
            const int n = lo + glid;
            const float* gp = partials + (size_t)g * BPG * NPG + glid;
            float a = 0.0f;
#pragma unroll
            for (int b2 = 0; b2 < BPG; ++b2) a += gp[(size_t)b2 * NPG];

            float x1v = fast_x ? xb[t * NN + n] : x[(size_t)n * 20 + 2 * t + 1];

            float uin[10];
            uin[0] = x1v;
#pragma unroll
            for (int k = 0; k < 8; ++k) uin[1 + k] = hid[k];
            uin[9] = a;

            float u1[32];
#pragma unroll
            for (int j = 0; j < 32; ++j) {
                float acc = s_m2b1[j];
#pragma unroll
                for (int i = 0; i < 10; ++i) acc += uin[i] * s_m2w1[i * 32 + j];
                u1[j] = reluf_(acc);
            }
#pragma unroll
            for (int k = 0; k < 8; ++k) {
                float acc = s_m2b2[k];
#pragma unroll
                for (int j = 0; j < 32; ++j) acc += u1[j] * s_m2w2[j * 8 + k];
                hid[k] = tanhf(reluf_(acc));
            }

            float o1[16];
#pragma unroll
            for (int l = 0; l < 16; ++l) {
                float acc = s_ob1[l];
#pragma unroll
                for (int k = 0; k < 8; ++k) acc += hid[k] * s_ow1[k * 16 + l];
                o1[l] = reluf_(acc);
            }
            float oo = s_ob2s;
#pragma unroll
            for (int l = 0; l < 16; ++l) oo += o1[l] * s_ow2[l];
            out[t * NN + n] = sigmoidf_(oo);

            if (t < TT - 1) {
                float feat[9];
                feat[0] = fast_x ? xa[(t + 1) * NN + n]
                                 : x[(size_t)n * 20 + 2 * (t + 1)];
#pragma unroll
                for (int k = 0; k < 8; ++k) feat[1 + k] = hid[k];
                msg_base[n] = mlp1_eval(feat, s_w1, s_b1, s_w2, s_b2, s_w3, s_b3s);
            }
        }
        // next iteration's grid.sync() publishes msg_base(t+1) to all groups
    }
}

extern "C" void kernel_launch(void* const* d_in, const int* in_sizes, int n_in,
                              void* d_out, int out_size, void* d_ws, size_t ws_size,
                              hipStream_t stream) {
    (void)in_sizes; (void)n_in; (void)out_size;
    const float* x    = (const float*)d_in[0];
    const int*   ei   = (const int*)d_in[1];
    const float* ea   = (const float*)d_in[2];
    const float* m1w1 = (const float*)d_in[3];
    const float* m1b1 = (const float*)d_in[4];
    const float* m1w2 = (const float*)d_in[5];
    const float* m1b2 = (const float*)d_in[6];
    const float* m1w3 = (const float*)d_in[7];
    const float* m1b3 = (const float*)d_in[8];
    const float* m2w1 = (const float*)d_in[9];
    const float* m2b1 = (const float*)d_in[10];
    const float* m2w2 = (const float*)d_in[11];
    const float* m2b2 = (const float*)d_in[12];
    const float* ow1  = (const float*)d_in[13];
    const float* ob1  = (const float*)d_in[14];
    const float* ow2  = (const float*)d_in[15];
    const float* ob2  = (const float*)d_in[16];
    float* out = (float*)d_out;

    // ws layout: msg_base[NN] | partials[8*32*6250] | ibar[16] | eaT[T*E] | xa[T*N] | xb[T*N]
    float* msg_base = (float*)d_ws;
    float* partials = msg_base + NN;
    int*   ibar     = (int*)(partials + (size_t)GROUPS * BPG * NPG);
    float* eaT      = (float*)(ibar + 16);
    float* xa       = eaT + (size_t)TT * EE;
    float* xb       = xa + (size_t)TT * NN;

    size_t need_base = ((size_t)NN + (size_t)GROUPS * BPG * NPG) * 4 + 64;
    size_t need_ea   = need_base + (size_t)TT * EE * 4;
    size_t need_x    = need_ea + (size_t)2 * TT * NN * 4;
    int fast_ea = (ws_size >= need_ea) ? 1 : 0;
    int fast_x  = (ws_size >= need_x) ? 1 : 0;

    void* args[] = {
        (void*)&x, (void*)&ei, (void*)&ea,
        (void*)&m1w1, (void*)&m1b1, (void*)&m1w2, (void*)&m1b2,
        (void*)&m1w3, (void*)&m1b3,
        (void*)&m2w1, (void*)&m2b1, (void*)&m2w2, (void*)&m2b2,
        (void*)&ow1, (void*)&ob1, (void*)&ow2, (void*)&ob2,
        (void*)&out, (void*)&msg_base, (void*)&partials,
        (void*)&ibar, (void*)&eaT, (void*)&xa, (void*)&xb,
        (void*)&fast_ea, (void*)&fast_x
    };
    hipLaunchCooperativeKernel((const void*)fused_kernel,
                               dim3(GRID_BLOCKS), dim3(BLOCK),
                               args, 0, stream);
}

// Round 7
// 1467.903 us; speedup vs baseline: 1.0071x; 1.0034x over previous
//
#include <hip/hip_runtime.h>

#define NN 50000
#define TT 10
#define EE 1000000
#define BLOCK 1024
#define GRID_BLOCKS 256
#define GROUPS 8
#define BPG 32               // blocks per group
#define NPG 6250             // nodes per group
#define CAP 131072           // records per (t,group) bucket; mean 125000, +18 sigma
#define MSGP 50048           // padded msg_v stride
#define CHUNK 4096           // edges per preprocess chunk
#define NCH ((EE + CHUNK - 1) / CHUNK)

__device__ __forceinline__ float sigmoidf_(float v) { return 1.0f / (1.0f + __expf(-v)); }
__device__ __forceinline__ float reluf_(float v) { return v > 0.0f ? v : 0.0f; }

__device__ __forceinline__ float mlp1_eval(const float* feat,
                                           const float* s_w1, const float* s_b1,
                                           const float* s_w2, const float* s_b2,
                                           const float* s_w3, float s_b3) {
    float h1[32];
#pragma unroll
    for (int j = 0; j < 32; ++j) {
        float acc = s_b1[j];
#pragma unroll
        for (int i = 0; i < 9; ++i) acc += feat[i] * s_w1[i * 32 + j];
        h1[j] = reluf_(acc);
    }
    float acc3 = s_b3;
#pragma unroll
    for (int j2 = 0; j2 < 32; ++j2) {
        float acc = s_b2[j2];
#pragma unroll
        for (int i = 0; i < 32; ++i) acc += h1[i] * s_w2[i * 32 + j2];
        acc3 += reluf_(acc) * s_w3[j2];
    }
    return sigmoidf_(acc3);
}

// Monotone-generation barrier: relaxed polls (no per-poll L2 invalidate),
// one acquire fence on exit. Counters never reset (no reset race).
__device__ __forceinline__ void arrive_wait(int* arrive, int* gen, int target, int nblocks) {
    __syncthreads();
    if (threadIdx.x == 0) {
        int old = __hip_atomic_fetch_add(arrive, 1, __ATOMIC_ACQ_REL, __HIP_MEMORY_SCOPE_AGENT);
        if (old == target * nblocks - 1) {
            __hip_atomic_store(gen, target, __ATOMIC_RELEASE, __HIP_MEMORY_SCOPE_AGENT);
        } else {
            while (__hip_atomic_load(gen, __ATOMIC_RELAXED, __HIP_MEMORY_SCOPE_AGENT) < target)
                __builtin_amdgcn_s_sleep(4);
        }
        __builtin_amdgcn_fence(__ATOMIC_ACQUIRE, "agent");
    }
    __syncthreads();
}

// ws counter layout (ints): [0]=devArrive [1]=devGen [2..9]=grpArrive [10..17]=grpGen
// [32..111]=gcnt[80]
__global__ void __launch_bounds__(BLOCK, 1)
fused_kernel(const float* __restrict__ x, const int* __restrict__ ei,
             const float* __restrict__ ea,
             const float* __restrict__ m1w1, const float* __restrict__ m1b1,
             const float* __restrict__ m1w2, const float* __restrict__ m1b2,
             const float* __restrict__ m1w3, const float* __restrict__ m1b3,
             const float* __restrict__ m2w1, const float* __restrict__ m2b1,
             const float* __restrict__ m2w2, const float* __restrict__ m2b2,
             const float* __restrict__ ow1, const float* __restrict__ ob1,
             const float* __restrict__ ow2, const float* __restrict__ ob2,
             float* __restrict__ out,
             int* __restrict__ ctrs, uint2* __restrict__ buckets,
             float* __restrict__ msg_v, float* __restrict__ partials,
             int fast) {
    __shared__ float s_w1[288], s_b1[32], s_w2[1024], s_b2[32], s_w3[32];
    __shared__ float s_m2w1[320], s_m2b1[32], s_m2w2[256], s_m2b2[8];
    __shared__ float s_ow1[128], s_ob1[16], s_ow2[16];
    __shared__ float s_b3s, s_ob2s;
    __shared__ float s_tab[NPG];
    __shared__ unsigned s_cnt[80], s_base[80];

    const int tid = threadIdx.x;
    for (int i = tid; i < 288; i += BLOCK) s_w1[i] = m1w1[i];
    for (int i = tid; i < 1024; i += BLOCK) s_w2[i] = m1w2[i];
    for (int i = tid; i < 320; i += BLOCK) s_m2w1[i] = m2w1[i];
    for (int i = tid; i < 256; i += BLOCK) s_m2w2[i] = m2w2[i];
    for (int i = tid; i < 128; i += BLOCK) s_ow1[i] = ow1[i];
    if (tid < 32) {
        s_b1[tid] = m1b1[tid];
        s_b2[tid] = m1b2[tid];
        s_w3[tid] = m1w3[tid];
        s_m2b1[tid] = m2b1[tid];
    }
    if (tid < 16) { s_ob1[tid] = ob1[tid]; s_ow2[tid] = ow2[tid]; }
    if (tid < 8) s_m2b2[tid] = m2b2[tid];
    if (tid == 0) { s_b3s = m1b3[0]; s_ob2s = ob2[0]; }
    __syncthreads();

    const int g = blockIdx.x & (GROUPS - 1);
    const int b = blockIdx.x >> 3;
    const int glid = b * BLOCK + tid;
    const int lo = g * NPG;
    int* devArr = ctrs + 0;
    int* devGen = ctrs + 1;
    int* grpArr = ctrs + 2 + g;
    int* grpGen = ctrs + 10 + g;
    int* gcnt   = ctrs + 32;

    // ---- Preprocess: bucket all (t,e) into per-(t,dstGroup) record lists ----
    if (fast) {
        for (int c = blockIdx.x; c < NCH; c += GRID_BLOCKS) {
            const int e = c * CHUNK + tid * 4;
            const bool valid = (e < EE);
            // pass 1: count records per (t,g) bucket
            for (int i = tid; i < 80; i += BLOCK) s_cnt[i] = 0;
            __syncthreads();
            if (valid) {
#pragma unroll
                for (int t = 0; t < TT; ++t) {
                    int4 d4 = *reinterpret_cast<const int4*>(ei + (size_t)TT * EE + (size_t)t * EE + e);
                    atomicAdd(&s_cnt[t * 8 + (d4.x / NPG)], 1u);
                    atomicAdd(&s_cnt[t * 8 + (d4.y / NPG)], 1u);
                    atomicAdd(&s_cnt[t * 8 + (d4.z / NPG)], 1u);
                    atomicAdd(&s_cnt[t * 8 + (d4.w / NPG)], 1u);
                }
            }
            __syncthreads();
            // reserve global ranges
            if (tid < 80) {
                unsigned n = s_cnt[tid];
                s_base[tid] = n ? (unsigned)__hip_atomic_fetch_add(&gcnt[tid], (int)n,
                                    __ATOMIC_RELAXED, __HIP_MEMORY_SCOPE_AGENT) : 0u;
                s_cnt[tid] = 0;
            }
            __syncthreads();
            // pass 2: write records
            if (valid) {
                // ea rows for my 4 edges: 10 floats each, contiguous
                float ear[4][10];
#pragma unroll
                for (int q = 0; q < 4; ++q) {
                    const float2* p = reinterpret_cast<const float2*>(ea + (size_t)(e + q) * TT);
#pragma unroll
                    for (int h = 0; h < 5; ++h) {
                        float2 v = p[h];
                        ear[q][2 * h] = v.x; ear[q][2 * h + 1] = v.y;
                    }
                }
#pragma unroll
                for (int t = 0; t < TT; ++t) {
                    int4 s4 = *reinterpret_cast<const int4*>(ei + (size_t)t * EE + e);
                    int4 d4 = *reinterpret_cast<const int4*>(ei + (size_t)TT * EE + (size_t)t * EE + e);
                    int ss[4] = {s4.x, s4.y, s4.z, s4.w};
                    int dd[4] = {d4.x, d4.y, d4.z, d4.w};
#pragma unroll
                    for (int q = 0; q < 4; ++q) {
                        int gg = dd[q] / NPG;
                        int k = t * 8 + gg;
                        unsigned off = s_base[k] + atomicAdd(&s_cnt[k], 1u);
                        if (off < CAP) {
                            uint2 rec;
                            rec.x = (unsigned)ss[q] | ((unsigned)(dd[q] - gg * NPG) << 16);
                            rec.y = __float_as_uint(ear[q][t]);
                            buckets[(size_t)k * CAP + off] = rec;
                        }
                    }
                }
            }
            __syncthreads();
        }
    }

    // ---- Init: hidden=0, msg_v[0] ----
    float hid[8];
#pragma unroll
    for (int k = 0; k < 8; ++k) hid[k] = 0.0f;

    if (glid < NPG) {
        const int n = lo + glid;
        float feat[9];
        feat[0] = x[(size_t)n * 20];
#pragma unroll
        for (int k = 0; k < 8; ++k) feat[1 + k] = 0.0f;
        msg_v[n] = mlp1_eval(feat, s_w1, s_b1, s_w2, s_b2, s_w3, s_b3s);
    }
    arrive_wait(devArr, devGen, 1, GRID_BLOCKS);   // preprocess + msg_v[0] visible

    // ---- Frame loop ----
    for (int t = 0; t < TT; ++t) {
        if (t > 0) arrive_wait(devArr, devGen, 1 + t, GRID_BLOCKS);

        for (int i = tid; i < NPG; i += BLOCK) s_tab[i] = 0.0f;
        __syncthreads();

        const float* msg = msg_v + (size_t)t * MSGP;
        if (fast) {
            const int k = t * 8 + g;
            int count = gcnt[k]; if (count > CAP) count = CAP;
            const uint2* bp = buckets + (size_t)k * CAP;
            for (int i = glid; i < count; i += BPG * BLOCK) {
                uint2 r = bp[i];
                float m = msg[r.x & 0xFFFFu] * __uint_as_float(r.y);
                atomicAdd(&s_tab[r.x >> 16], m);
            }
        } else {
            // fallback: scan raw edges, filter dst in my group range
            const int* srcp = ei + (size_t)t * EE;
            const int* dstp = ei + (size_t)TT * EE + (size_t)t * EE;
            for (int e = glid * 4; e < EE; e += BPG * BLOCK * 4) {
                int4 d4 = *reinterpret_cast<const int4*>(dstp + e);
                unsigned u0 = (unsigned)(d4.x - lo), u1 = (unsigned)(d4.y - lo);
                unsigned u2 = (unsigned)(d4.z - lo), u3 = (unsigned)(d4.w - lo);
                bool p0 = u0 < NPG, p1 = u1 < NPG, p2 = u2 < NPG, p3 = u3 < NPG;
                if (p0 | p1 | p2 | p3) {
                    int4 s4 = *reinterpret_cast<const int4*>(srcp + e);
                    if (p0) atomicAdd(&s_tab[u0], msg[s4.x] * ea[(size_t)(e + 0) * TT + t]);
                    if (p1) atomicAdd(&s_tab[u1], msg[s4.y] * ea[(size_t)(e + 1) * TT + t]);
                    if (p2) atomicAdd(&s_tab[u2], msg[s4.z] * ea[(size_t)(e + 2) * TT + t]);
                    if (p3) atomicAdd(&s_tab[u3], msg[s4.w] * ea[(size_t)(e + 3) * TT + t]);
                }
            }
        }
        __syncthreads();

        // publish this block's partial table
        {
            float* myP = partials + ((size_t)g * BPG + b) * NPG;
            for (int i = tid; i < NPG; i += BLOCK) myP[i] = s_tab[i];
        }
        arrive_wait(grpArr, grpGen, t + 1, BPG);   // group-internal handoff

        // node phase (blocks 0..6 of each group own its 6250 nodes)
        if (glid < NPG) {
            const int n = lo + glid;
            const float* gp = partials + (size_t)g * BPG * NPG + glid;
            float a = 0.0f;
#pragma unroll
            for (int b2 = 0; b2 < BPG; ++b2) a += gp[(size_t)b2 * NPG];

            float uin[10];
            uin[0] = x[(size_t)n * 20 + 2 * t + 1];
#pragma unroll
            for (int k = 0; k < 8; ++k) uin[1 + k] = hid[k];
            uin[9] = a;

            float u1[32];
#pragma unroll
            for (int j = 0; j < 32; ++j) {
                float acc = s_m2b1[j];
#pragma unroll
                for (int i = 0; i < 10; ++i) acc += uin[i] * s_m2w1[i * 32 + j];
                u1[j] = reluf_(acc);
            }
#pragma unroll
            for (int k = 0; k < 8; ++k) {
                float acc = s_m2b2[k];
#pragma unroll
                for (int j = 0; j < 32; ++j) acc += u1[j] * s_m2w2[j * 8 + k];
                hid[k] = tanhf(reluf_(acc));
            }

            float o1[16];
#pragma unroll
            for (int l = 0; l < 16; ++l) {
                float acc = s_ob1[l];
#pragma unroll
                for (int k = 0; k < 8; ++k) acc += hid[k] * s_ow1[k * 16 + l];
                o1[l] = reluf_(acc);
            }
            float oo = s_ob2s;
#pragma unroll
            for (int l = 0; l < 16; ++l) oo += o1[l] * s_ow2[l];
            out[t * NN + n] = sigmoidf_(oo);

            if (t < TT - 1) {
                float feat[9];
                feat[0] = x[(size_t)n * 20 + 2 * (t + 1)];
#pragma unroll
                for (int k = 0; k < 8; ++k) feat[1 + k] = hid[k];
                msg_v[(size_t)(t + 1) * MSGP + n] =
                    mlp1_eval(feat, s_w1, s_b1, s_w2, s_b2, s_w3, s_b3s);
            }
        }
    }
}

extern "C" void kernel_launch(void* const* d_in, const int* in_sizes, int n_in,
                              void* d_out, int out_size, void* d_ws, size_t ws_size,
                              hipStream_t stream) {
    (void)in_sizes; (void)n_in; (void)out_size;
    const float* x    = (const float*)d_in[0];
    const int*   ei   = (const int*)d_in[1];
    const float* ea   = (const float*)d_in[2];
    const float* m1w1 = (const float*)d_in[3];
    const float* m1b1 = (const float*)d_in[4];
    const float* m1w2 = (const float*)d_in[5];
    const float* m1b2 = (const float*)d_in[6];
    const float* m1w3 = (const float*)d_in[7];
    const float* m1b3 = (const float*)d_in[8];
    const float* m2w1 = (const float*)d_in[9];
    const float* m2b1 = (const float*)d_in[10];
    const float* m2w2 = (const float*)d_in[11];
    const float* m2b2 = (const float*)d_in[12];
    const float* ow1  = (const float*)d_in[13];
    const float* ob1  = (const float*)d_in[14];
    const float* ow2  = (const float*)d_in[15];
    const float* ob2  = (const float*)d_in[16];
    float* out = (float*)d_out;

    // ws layout: ctrs(1024 B) | buckets(80*CAP*8 B) | msg_v(10*MSGP f) | partials(8*32*NPG f)
    char* base = (char*)d_ws;
    int*   ctrs = (int*)base;
    uint2* buckets = (uint2*)(base + 1024);
    size_t buckets_bytes = (size_t)80 * CAP * sizeof(uint2);
    size_t need_fast = 1024 + buckets_bytes
                     + (size_t)TT * MSGP * 4 + (size_t)GROUPS * BPG * NPG * 4;
    int fast = (ws_size >= need_fast) ? 1 : 0;

    float* msg_v;
    float* partials;
    if (fast) {
        msg_v = (float*)(base + 1024 + buckets_bytes);
    } else {
        msg_v = (float*)(base + 1024);
    }
    partials = msg_v + (size_t)TT * MSGP;

    // zero counters (stream-ordered; capture-safe; same work every call)
    hipMemsetAsync(ctrs, 0, 1024, stream);

    void* args[] = {
        (void*)&x, (void*)&ei, (void*)&ea,
        (void*)&m1w1, (void*)&m1b1, (void*)&m1w2, (void*)&m1b2,
        (void*)&m1w3, (void*)&m1b3,
        (void*)&m2w1, (void*)&m2b1, (void*)&m2w2, (void*)&m2b2,
        (void*)&ow1, (void*)&ob1, (void*)&ow2, (void*)&ob2,
        (void*)&out, (void*)&ctrs, (void*)&buckets,
        (void*)&msg_v, (void*)&partials, (void*)&fast
    };
    hipLaunchCooperativeKernel((const void*)fused_kernel,
                               dim3(GRID_BLOCKS), dim3(BLOCK),
                               args, 0, stream);
}